// Round 8
// baseline (798.747 us; speedup 1.0000x reference)
//
#include <hip/hip_runtime.h>
#include <hip/hip_bf16.h>

#define N_NODES 100000
#define N_EDGES 3200000
#define D_IN 256
#define HID 256
#define NC 40
#define SCAN_B 391                         /* scan blocks of 256 nodes */

typedef unsigned short u16;
typedef unsigned int u32;
typedef __attribute__((ext_vector_type(8))) short bf16x8;
typedef __attribute__((ext_vector_type(4))) float f32x4;
typedef __attribute__((ext_vector_type(2))) float f32x2;

static __device__ __forceinline__ float bf2f(u16 u) {
  union { unsigned int i; float f; } c; c.i = ((unsigned int)u) << 16; return c.f;
}
static __device__ __forceinline__ u16 f2bf(float f) {
  union { float f; unsigned int i; } c; c.f = f;
  unsigned int x = c.i;
  x += 0x7fffu + ((x >> 16) & 1u);   // round-to-nearest-even
  return (u16)(x >> 16);
}

// ---- direct CSR build: deg -> scan -> scatter -------------------------------
__global__ __launch_bounds__(256) void k_zdeg(int* __restrict__ deg) {
  int i = blockIdx.x * 256 + threadIdx.x;
  if (i < N_NODES) deg[i] = 0;
}

__global__ __launch_bounds__(256) void k_deg(const int* __restrict__ ei,
    int* __restrict__ deg) {
  int e = blockIdx.x * 256 + threadIdx.x;
  if (e < N_EDGES) {
    unsigned s = (unsigned)ei[e];
    unsigned d = (unsigned)ei[N_EDGES + e];
    if (s < N_NODES && d < N_NODES) atomicAdd(&deg[d], 1);
  }
}

__global__ __launch_bounds__(256) void k_scan1(const int* __restrict__ deg,
    int* __restrict__ bt) {
  __shared__ int s[256];
  int b = blockIdx.x, t = threadIdx.x;
  int n = b * 256 + t;
  int v = (n < N_NODES) ? deg[n] : 0;
  s[t] = v;
  __syncthreads();
  for (int off = 1; off < 256; off <<= 1) {
    int a = (t >= off) ? s[t - off] : 0;
    __syncthreads();
    s[t] += a;
    __syncthreads();
  }
  if (t == 255) bt[b] = s[255];
}

__global__ void k_scan2(const int* __restrict__ bt, int* __restrict__ btoff) {
  __shared__ int s[512];
  int t = threadIdx.x;
  int v = (t < SCAN_B) ? bt[t] : 0;
  s[t] = v;
  __syncthreads();
  for (int off = 1; off < 512; off <<= 1) {
    int a = (t >= off) ? s[t - off] : 0;
    __syncthreads();
    s[t] += a;
    __syncthreads();
  }
  if (t < SCAN_B) btoff[t] = s[t] - v;         // exclusive
}

__global__ __launch_bounds__(256) void k_scan3(const int* __restrict__ deg,
    const int* __restrict__ btoff, int* __restrict__ rp, int* __restrict__ re,
    float* __restrict__ dinv, int* __restrict__ cur) {
  __shared__ int s[256];
  int b = blockIdx.x, t = threadIdx.x;
  int n = b * 256 + t;
  int v = (n < N_NODES) ? deg[n] : 0;
  s[t] = v;
  __syncthreads();
  for (int off = 1; off < 256; off <<= 1) {
    int a = (t >= off) ? s[t - off] : 0;
    __syncthreads();
    s[t] += a;
    __syncthreads();
  }
  if (n < N_NODES) {
    int excl = btoff[b] + s[t] - v;
    rp[n] = excl;
    re[n] = excl + v;
    dinv[n] = rsqrtf((float)v + 1.0f);         // +1 self-loop
    cur[n] = excl;
  }
}

__global__ __launch_bounds__(256) void k_scat(const int* __restrict__ ei,
    int* __restrict__ cur, int* __restrict__ ed) {
  int e = blockIdx.x * 256 + threadIdx.x;
  if (e < N_EDGES) {
    unsigned s = (unsigned)ei[e];
    unsigned d = (unsigned)ei[N_EDGES + e];
    if (s < N_NODES && d < N_NODES) {
      int pos = atomicAdd(&cur[d], 1);
      ed[pos] = (int)s;
    }
  }
}

// ---- weight transposes ------------------------------------------------------
__global__ void k_w1t(const float* __restrict__ W1, u16* __restrict__ w1t) {
  int n = blockIdx.x, k = threadIdx.x;         // 256 x 256
  w1t[n * 256 + k] = f2bf(W1[k * 256 + n]);
}
__global__ void k_w2t(const float* __restrict__ W2, u16* __restrict__ w2t) {
  int n = blockIdx.x, k = threadIdx.x;         // 48 x 256 (pad cols 40..47 = 0)
  w2t[n * 256 + k] = (n < NC) ? f2bf(W2[k * NC + n]) : (u16)0;
}

// ---- GEMM1 (MFMA bf16): y'[100000,256]fp8 = dinv .* (x @ W1), 128x128 tile --
// grid = (2, nRowBlocks): col-block fastest so both col-blocks of a row tile
// run adjacently -> x tile read once from HBM, second read hits L2/L3.
__global__ __launch_bounds__(256) void k_gemm1(const float* __restrict__ x,
    const u16* __restrict__ w1t, const float* __restrict__ dinv,
    unsigned char* __restrict__ y) {
  __shared__ char smem[20480];
  short* sA = (short*)smem;                    // [128][40] bf16 (pad 8)
  short* sB = (short*)(smem + 10240);          // [128][40]
  float* sdinv = (float*)(smem + 18432);       // 128 floats (epilogue only)
  int tid = threadIdx.x;
  int wave = tid >> 6, lane = tid & 63;
  int lq = lane >> 4, lr = lane & 15;
  int wm = (wave >> 1) * 64, wn = (wave & 1) * 64;
  int row0 = blockIdx.y * 128;
  int col0 = blockIdx.x * 128;
  int sr = tid >> 1;                           // staging row 0..127
  int sh = (tid & 1) * 16;                     // k-half in elements
  int arow = row0 + sr;
  bool aval = arow < N_NODES;
  const float* axf = x + (size_t)arow * 256 + sh;
  const u16* bx = w1t + (size_t)(col0 + sr) * 256 + sh;
  f32x4 acc[4][4] = {};
  for (int k0 = 0; k0 < 256; k0 += 32) {
    float4 f0 = {}, f1 = {}, f2 = {}, f3 = {};
    if (aval) {
      f0 = *(const float4*)(axf + k0);
      f1 = *(const float4*)(axf + k0 + 4);
      f2 = *(const float4*)(axf + k0 + 8);
      f3 = *(const float4*)(axf + k0 + 12);
    }
    uint4 vb0 = *(const uint4*)(bx + k0);
    uint4 vb1 = *(const uint4*)(bx + k0 + 8);
    uint4 pa0, pa1;
    pa0.x = (u32)f2bf(f0.x) | ((u32)f2bf(f0.y) << 16);
    pa0.y = (u32)f2bf(f0.z) | ((u32)f2bf(f0.w) << 16);
    pa0.z = (u32)f2bf(f1.x) | ((u32)f2bf(f1.y) << 16);
    pa0.w = (u32)f2bf(f1.z) | ((u32)f2bf(f1.w) << 16);
    pa1.x = (u32)f2bf(f2.x) | ((u32)f2bf(f2.y) << 16);
    pa1.y = (u32)f2bf(f2.z) | ((u32)f2bf(f2.w) << 16);
    pa1.z = (u32)f2bf(f3.x) | ((u32)f2bf(f3.y) << 16);
    pa1.w = (u32)f2bf(f3.z) | ((u32)f2bf(f3.w) << 16);
    __syncthreads();
    *(uint4*)&sA[sr * 40 + sh] = pa0;
    *(uint4*)&sA[sr * 40 + sh + 8] = pa1;
    *(uint4*)&sB[sr * 40 + sh] = vb0;
    *(uint4*)&sB[sr * 40 + sh + 8] = vb1;
    __syncthreads();
    bf16x8 af[4], bfr[4];
#pragma unroll
    for (int mt = 0; mt < 4; ++mt)
      af[mt] = *(const bf16x8*)&sA[(wm + mt * 16 + lr) * 40 + lq * 8];
#pragma unroll
    for (int nt = 0; nt < 4; ++nt)
      bfr[nt] = *(const bf16x8*)&sB[(wn + nt * 16 + lr) * 40 + lq * 8];
#pragma unroll
    for (int mt = 0; mt < 4; ++mt)
#pragma unroll
      for (int nt = 0; nt < 4; ++nt)
        acc[mt][nt] = __builtin_amdgcn_mfma_f32_16x16x32_bf16(
            af[mt], bfr[nt], acc[mt][nt], 0, 0, 0);
  }
  __syncthreads();
  if (tid < 128) {
    int rr = row0 + tid;
    sdinv[tid] = (rr < N_NODES) ? dinv[rr] : 0.f;
  }
  __syncthreads();
#pragma unroll
  for (int mt = 0; mt < 4; ++mt)
#pragma unroll
    for (int nt = 0; nt < 4; ++nt) {
      int c = wn + nt * 16 + lr;
#pragma unroll
      for (int i = 0; i < 4; ++i) {
        int r = wm + mt * 16 + lq * 4 + i;
        float sv = sdinv[r] * acc[mt][nt][i];
        int pk = __builtin_amdgcn_cvt_pk_fp8_f32(sv, sv, 0, false);
        smem[r * 144 + c] = (char)(pk & 0xFF);
      }
    }
  __syncthreads();
  if (aval) {
    unsigned char* dst = y + (size_t)arow * 256 + col0 + (tid & 1) * 64;
    const char* srcp = smem + sr * 144 + (tid & 1) * 64;
#pragma unroll
    for (int j = 0; j < 4; ++j)
      ((uint4*)dst)[j] = *(const uint4*)(srcp + j * 16);
  }
}

// ---- SpMM1: h1 = relu(dinv*(y'[row]+sum y'[src])+b1) ------------------------
// Deep-MLP gather: lane=(g,p), g=edge slot 0..3, p=16B chunk. Launched as two
// half-row dispatches (row0 = 0, N_NODES/2) for profiler visibility.
#define ACC8(U) do { \
    acc[0] += __builtin_amdgcn_cvt_pk_f32_fp8((U).x, false); \
    acc[1] += __builtin_amdgcn_cvt_pk_f32_fp8((U).x, true);  \
    acc[2] += __builtin_amdgcn_cvt_pk_f32_fp8((U).y, false); \
    acc[3] += __builtin_amdgcn_cvt_pk_f32_fp8((U).y, true);  \
    acc[4] += __builtin_amdgcn_cvt_pk_f32_fp8((U).z, false); \
    acc[5] += __builtin_amdgcn_cvt_pk_f32_fp8((U).z, true);  \
    acc[6] += __builtin_amdgcn_cvt_pk_f32_fp8((U).w, false); \
    acc[7] += __builtin_amdgcn_cvt_pk_f32_fp8((U).w, true);  \
  } while (0)

__global__ __launch_bounds__(256) void k_spmm1(const uint4* __restrict__ y16,
    const int* __restrict__ ed, const int* __restrict__ rp,
    const int* __restrict__ re, const float* __restrict__ dinv,
    const float* __restrict__ b1, u16* __restrict__ h1, int row0) {
  int lane = threadIdx.x & 63;
  int row = row0 + (blockIdx.x << 2) + (threadIdx.x >> 6);
  int g = lane >> 4, p = lane & 15;
  float di = dinv[row];
  uint4 sv = y16[(size_t)row * 16 + p];
  f32x2 acc[8];
  f32x2 z2 = {0.f, 0.f};
  if (g == 0) {
    acc[0] = __builtin_amdgcn_cvt_pk_f32_fp8(sv.x, false);
    acc[1] = __builtin_amdgcn_cvt_pk_f32_fp8(sv.x, true);
    acc[2] = __builtin_amdgcn_cvt_pk_f32_fp8(sv.y, false);
    acc[3] = __builtin_amdgcn_cvt_pk_f32_fp8(sv.y, true);
    acc[4] = __builtin_amdgcn_cvt_pk_f32_fp8(sv.z, false);
    acc[5] = __builtin_amdgcn_cvt_pk_f32_fp8(sv.z, true);
    acc[6] = __builtin_amdgcn_cvt_pk_f32_fp8(sv.w, false);
    acc[7] = __builtin_amdgcn_cvt_pk_f32_fp8(sv.w, true);
  } else {
#pragma unroll
    for (int i = 0; i < 8; ++i) acc[i] = z2;
  }
  int e = rp[row], e1 = re[row];
  if (e + 16 <= e1) {
    int s0 = ed[e + g], s1 = ed[e + 4 + g];
    int s2 = ed[e + 8 + g], s3 = ed[e + 12 + g];
    while (true) {
      uint4 u0 = y16[(size_t)s0 * 16 + p];
      uint4 u1 = y16[(size_t)s1 * 16 + p];
      uint4 u2 = y16[(size_t)s2 * 16 + p];
      uint4 u3 = y16[(size_t)s3 * 16 + p];
      e += 16;
      bool more = (e + 16 <= e1);
      if (more) {
        s0 = ed[e + g]; s1 = ed[e + 4 + g];
        s2 = ed[e + 8 + g]; s3 = ed[e + 12 + g];
      }
      ACC8(u0);
      ACC8(u1);
      ACC8(u2);
      ACC8(u3);
      if (!more) break;
    }
  }
  for (; e + 4 <= e1; e += 4) {
    int s0 = ed[e + g];
    uint4 u0 = y16[(size_t)s0 * 16 + p];
    ACC8(u0);
  }
  int rem = e1 - e;
  if (rem > 0) {
    int s0 = ed[e + (g < rem ? g : 0)];
    uint4 u0 = y16[(size_t)s0 * 16 + p];
    if (g < rem) ACC8(u0);
  }
#pragma unroll
  for (int i = 0; i < 8; ++i) {
    acc[i].x += __shfl_xor(acc[i].x, 16);
    acc[i].y += __shfl_xor(acc[i].y, 16);
    acc[i].x += __shfl_xor(acc[i].x, 32);
    acc[i].y += __shfl_xor(acc[i].y, 32);
  }
  if (g == 0) {
    const float4* bb4 = (const float4*)(b1 + p * 16);
    u16 o[16];
#pragma unroll
    for (int i = 0; i < 4; ++i) {
      float4 bb = bb4[i];
      float a0 = fmaxf(di * acc[2 * i].x + bb.x, 0.f);
      float a1 = fmaxf(di * acc[2 * i].y + bb.y, 0.f);
      float a2 = fmaxf(di * acc[2 * i + 1].x + bb.z, 0.f);
      float a3 = fmaxf(di * acc[2 * i + 1].y + bb.w, 0.f);
      o[4 * i + 0] = f2bf(a0);
      o[4 * i + 1] = f2bf(a1);
      o[4 * i + 2] = f2bf(a2);
      o[4 * i + 3] = f2bf(a3);
    }
    u16* dst = h1 + (size_t)row * HID + p * 16;
    *(uint4*)dst = *(const uint4*)&o[0];
    *(uint4*)(dst + 8) = *(const uint4*)&o[8];
  }
}

// ---- GEMM2 (MFMA bf16): z'[100000,64]bf16 = dinv .* (h1 @ W2), padded cols --
__global__ __launch_bounds__(256) void k_gemm2(const u16* __restrict__ h1,
    const u16* __restrict__ w2t, const float* __restrict__ dinv,
    u16* __restrict__ zbp) {
  __shared__ char smem[16384];
  short* sA = (short*)smem;                    // [128][40] bf16
  short* sB = (short*)(smem + 10240);          // [48][40]
  float* sdinv = (float*)(smem + 14336);       // 128 floats
  u16* sC = (u16*)smem;                        // [128][56] epilogue overlay
  int tid = threadIdx.x;
  int wave = tid >> 6, lane = tid & 63;
  int lq = lane >> 4, lr = lane & 15;
  int wm = wave * 32;
  int row0 = blockIdx.x * 128;
  int sr = tid >> 1;
  int sh = (tid & 1) * 16;
  int arow = row0 + sr;
  bool aval = arow < N_NODES;
  const u16* ax = h1 + (size_t)arow * 256 + sh;
  int br = tid >> 1;                           // B staging row (t<96)
  const u16* bx = w2t + (size_t)br * 256 + sh;
  if (tid < 128) {
    int rr = row0 + tid;
    sdinv[tid] = (rr < N_NODES) ? dinv[rr] : 0.f;
  }
  f32x4 acc[2][3] = {};
  for (int k0 = 0; k0 < 256; k0 += 32) {
    uint4 a0 = {}, a1 = {};
    if (aval) {
      a0 = *(const uint4*)(ax + k0);
      a1 = *(const uint4*)(ax + k0 + 8);
    }
    uint4 b0 = {}, b1v = {};
    if (tid < 96) {
      b0 = *(const uint4*)(bx + k0);
      b1v = *(const uint4*)(bx + k0 + 8);
    }
    __syncthreads();
    *(uint4*)&sA[sr * 40 + sh] = a0;
    *(uint4*)&sA[sr * 40 + sh + 8] = a1;
    if (tid < 96) {
      *(uint4*)&sB[br * 40 + sh] = b0;
      *(uint4*)&sB[br * 40 + sh + 8] = b1v;
    }
    __syncthreads();
    bf16x8 af[2], bfr[3];
#pragma unroll
    for (int mt = 0; mt < 2; ++mt)
      af[mt] = *(const bf16x8*)&sA[(wm + mt * 16 + lr) * 40 + lq * 8];
#pragma unroll
    for (int nt = 0; nt < 3; ++nt)
      bfr[nt] = *(const bf16x8*)&sB[(nt * 16 + lr) * 40 + lq * 8];
#pragma unroll
    for (int mt = 0; mt < 2; ++mt)
#pragma unroll
      for (int nt = 0; nt < 3; ++nt)
        acc[mt][nt] = __builtin_amdgcn_mfma_f32_16x16x32_bf16(
            af[mt], bfr[nt], acc[mt][nt], 0, 0, 0);
  }
  __syncthreads();
#pragma unroll
  for (int mt = 0; mt < 2; ++mt)
#pragma unroll
    for (int nt = 0; nt < 3; ++nt) {
      int c = nt * 16 + lr;
#pragma unroll
      for (int i = 0; i < 4; ++i) {
        int r = wm + mt * 16 + lq * 4 + i;
        sC[r * 56 + c] = f2bf(sdinv[r] * acc[mt][nt][i]);
      }
    }
  __syncthreads();
  if (tid < 128) {
    int orow = row0 + tid;
    if (orow < N_NODES) {
      u16* dst = zbp + (size_t)orow * 64;      // 128 B per row, padded
#pragma unroll
      for (int j = 0; j < 6; ++j)
        ((uint4*)dst)[j] = *(const uint4*)&sC[tid * 56 + j * 8];
      uint4 z = {};
      ((uint4*)dst)[6] = z;
      ((uint4*)dst)[7] = z;
    }
  }
}

// ---- SpMM2 + bias + log_softmax fused, deep-MLP wide-gather -----------------
#define ZACC(U) do { \
    acc[0] += __uint_as_float((U).x << 16); \
    acc[1] += __uint_as_float((U).x & 0xFFFF0000u); \
    acc[2] += __uint_as_float((U).y << 16); \
    acc[3] += __uint_as_float((U).y & 0xFFFF0000u); \
    acc[4] += __uint_as_float((U).z << 16); \
    acc[5] += __uint_as_float((U).z & 0xFFFF0000u); \
    acc[6] += __uint_as_float((U).w << 16); \
    acc[7] += __uint_as_float((U).w & 0xFFFF0000u); \
  } while (0)

__global__ __launch_bounds__(256) void k_spmm2(const uint4* __restrict__ zb4,
    const int* __restrict__ ed, const int* __restrict__ rp,
    const int* __restrict__ re, const float* __restrict__ dinv,
    const float* __restrict__ b2, float* __restrict__ out, int row0) {
  int lane = threadIdx.x & 63;
  int row = row0 + (blockIdx.x << 2) + (threadIdx.x >> 6);
  int g = lane >> 3, p = lane & 7;
  float di = dinv[row];
  float acc[8];
  uint4 sv = zb4[(size_t)row * 8 + p];
  if (g == 0) {
    acc[0] = __uint_as_float(sv.x << 16);
    acc[1] = __uint_as_float(sv.x & 0xFFFF0000u);
    acc[2] = __uint_as_float(sv.y << 16);
    acc[3] = __uint_as_float(sv.y & 0xFFFF0000u);
    acc[4] = __uint_as_float(sv.z << 16);
    acc[5] = __uint_as_float(sv.z & 0xFFFF0000u);
    acc[6] = __uint_as_float(sv.w << 16);
    acc[7] = __uint_as_float(sv.w & 0xFFFF0000u);
  } else {
#pragma unroll
    for (int i = 0; i < 8; ++i) acc[i] = 0.f;
  }
  int e = rp[row], e1 = re[row];
  if (e + 32 <= e1) {
    int s0 = ed[e + g], s1 = ed[e + 8 + g];
    int s2 = ed[e + 16 + g], s3 = ed[e + 24 + g];
    while (true) {
      uint4 u0 = zb4[(size_t)s0 * 8 + p];
      uint4 u1 = zb4[(size_t)s1 * 8 + p];
      uint4 u2 = zb4[(size_t)s2 * 8 + p];
      uint4 u3 = zb4[(size_t)s3 * 8 + p];
      e += 32;
      bool more = (e + 32 <= e1);
      if (more) {
        s0 = ed[e + g]; s1 = ed[e + 8 + g];
        s2 = ed[e + 16 + g]; s3 = ed[e + 24 + g];
      }
      ZACC(u0);
      ZACC(u1);
      ZACC(u2);
      ZACC(u3);
      if (!more) break;
    }
  }
  for (; e + 8 <= e1; e += 8) {
    int s0 = ed[e + g];
    uint4 u0 = zb4[(size_t)s0 * 8 + p];
    ZACC(u0);
  }
  int rem = e1 - e;
  if (g < rem) {
    int s0 = ed[e + g];
    uint4 u0 = zb4[(size_t)s0 * 8 + p];
    ZACC(u0);
  }
#pragma unroll
  for (int i = 0; i < 8; ++i) {
    acc[i] += __shfl_xor(acc[i], 8);
    acc[i] += __shfl_xor(acc[i], 16);
    acc[i] += __shfl_xor(acc[i], 32);
  }
  bool valid = p < 5;                          // cols p*8..p*8+7 < 40
  float val[8];
  if (valid) {
    float4 bb0 = *(const float4*)(b2 + p * 8);
    float4 bb1 = *(const float4*)(b2 + p * 8 + 4);
    val[0] = di * acc[0] + bb0.x;
    val[1] = di * acc[1] + bb0.y;
    val[2] = di * acc[2] + bb0.z;
    val[3] = di * acc[3] + bb0.w;
    val[4] = di * acc[4] + bb1.x;
    val[5] = di * acc[5] + bb1.y;
    val[6] = di * acc[6] + bb1.z;
    val[7] = di * acc[7] + bb1.w;
  } else {
#pragma unroll
    for (int i = 0; i < 8; ++i) val[i] = 0.f;
  }
  float mv = -3.0e38f;
  if (valid) {
#pragma unroll
    for (int i = 0; i < 8; ++i) mv = fmaxf(mv, val[i]);
  }
  mv = fmaxf(mv, __shfl_xor(mv, 1));
  mv = fmaxf(mv, __shfl_xor(mv, 2));
  mv = fmaxf(mv, __shfl_xor(mv, 4));
  float sum = 0.f;
  if (valid) {
#pragma unroll
    for (int i = 0; i < 8; ++i) sum += expf(val[i] - mv);
  }
  sum += __shfl_xor(sum, 1);
  sum += __shfl_xor(sum, 2);
  sum += __shfl_xor(sum, 4);
  float ls = logf(sum);
  if (g == 0 && valid) {
    float4 o0, o1;
    o0.x = val[0] - mv - ls; o0.y = val[1] - mv - ls;
    o0.z = val[2] - mv - ls; o0.w = val[3] - mv - ls;
    o1.x = val[4] - mv - ls; o1.y = val[5] - mv - ls;
    o1.z = val[6] - mv - ls; o1.w = val[7] - mv - ls;
    float* dst = out + (size_t)row * NC + p * 8;
    *(float4*)dst = o0;
    *(float4*)(dst + 4) = o1;
  }
}

extern "C" void kernel_launch(void* const* d_in, const int* in_sizes, int n_in,
                              void* d_out, int out_size, void* d_ws, size_t ws_size,
                              hipStream_t stream) {
  const float* x  = (const float*)d_in[0];
  const int*   ei = (const int*)d_in[1];
  const float* W1 = (const float*)d_in[2];
  const float* b1 = (const float*)d_in[3];
  const float* W2 = (const float*)d_in[4];
  const float* b2 = (const float*)d_in[5];
  float* out = (float*)d_out;

  char* ws = (char*)d_ws;
  size_t off = 0;
  auto alloc = [&](size_t bytes) {
    char* p = ws + off;
    off = (off + bytes + 255) & ~(size_t)255;
    return p;
  };
  int*   deg    = (int*)  alloc((size_t)N_NODES * 4);
  int*   bt     = (int*)  alloc((size_t)SCAN_B * 4);
  int*   btoff  = (int*)  alloc((size_t)SCAN_B * 4);
  int*   rp     = (int*)  alloc((size_t)N_NODES * 4);
  int*   re     = (int*)  alloc((size_t)N_NODES * 4);
  int*   cur    = (int*)  alloc((size_t)N_NODES * 4);
  float* dinv   = (float*)alloc((size_t)N_NODES * 4);
  int*   ed     = (int*)  alloc((size_t)N_EDGES * 4);           // 12.8 MB packed
  unsigned char* y = (unsigned char*)alloc((size_t)N_NODES * 256); // 25.6 MB fp8
  u16*   w1t    = (u16*)  alloc((size_t)256 * 256 * 2);
  u16*   w2t    = (u16*)  alloc((size_t)48 * 256 * 2);
  u16*   h1     = (u16*)  alloc((size_t)N_NODES * HID * 2);     // 51.2 MB
  u16*   zbp    = (u16*)  alloc((size_t)N_NODES * 64 * 2);      // 12.8 MB padded

  k_zdeg<<<SCAN_B, 256, 0, stream>>>(deg);
  k_deg<<<(N_EDGES + 255) / 256, 256, 0, stream>>>(ei, deg);
  k_scan1<<<SCAN_B, 256, 0, stream>>>(deg, bt);
  k_scan2<<<1, 512, 0, stream>>>(bt, btoff);
  k_scan3<<<SCAN_B, 256, 0, stream>>>(deg, btoff, rp, re, dinv, cur);
  k_scat<<<(N_EDGES + 255) / 256, 256, 0, stream>>>(ei, cur, ed);
  k_w1t<<<256, 256, 0, stream>>>(W1, w1t);
  k_w2t<<<48, 256, 0, stream>>>(W2, w2t);
  k_gemm1<<<dim3(2, (N_NODES + 127) / 128), 256, 0, stream>>>(x, w1t, dinv, y);
  k_spmm1<<<N_NODES / 8, 256, 0, stream>>>((const uint4*)y, ed, rp, re, dinv, b1, h1, 0);
  k_spmm1<<<N_NODES / 8, 256, 0, stream>>>((const uint4*)y, ed, rp, re, dinv, b1, h1, N_NODES / 2);
  k_gemm2<<<(N_NODES + 127) / 128, 256, 0, stream>>>(h1, w2t, dinv, zbp);
  k_spmm2<<<N_NODES / 8, 256, 0, stream>>>((const uint4*)zbp, ed, rp, re, dinv, b2, out, 0);
  k_spmm2<<<N_NODES / 8, 256, 0, stream>>>((const uint4*)zbp, ed, rp, re, dinv, b2, out, N_NODES / 2);
}

// Round 9
// 481.312 us; speedup vs baseline: 1.6595x; 1.6595x over previous
//
#include <hip/hip_runtime.h>
#include <hip/hip_bf16.h>

#define N_NODES 100000
#define N_EDGES 3200000
#define D_IN 256
#define HID 256
#define NC 40
#define NBUCK 391                          /* buckets of 256 dst nodes */
#define CHUNK 8192
#define BIN1_BLOCKS ((N_EDGES + CHUNK - 1) / CHUNK)  /* 391 */
#define BCAP 16384                         /* padded slots per bucket */
#define NPADE (NBUCK * BCAP)               /* 6406144 padded edge slots */

typedef unsigned short u16;
typedef unsigned int u32;
typedef __attribute__((ext_vector_type(8))) short bf16x8;
typedef __attribute__((ext_vector_type(4))) float f32x4;
typedef __attribute__((ext_vector_type(2))) float f32x2;

static __device__ __forceinline__ float bf2f(u16 u) {
  union { unsigned int i; float f; } c; c.i = ((unsigned int)u) << 16; return c.f;
}
static __device__ __forceinline__ u16 f2bf(float f) {
  union { float f; unsigned int i; } c; c.f = f;
  unsigned int x = c.i;
  x += 0x7fffu + ((x >> 16) & 1u);   // round-to-nearest-even
  return (u16)(x >> 16);
}

// ---- init per-bucket cursors to padded bases --------------------------------
__global__ void k_zero(int* __restrict__ gcur) {
  int i = blockIdx.x * 256 + threadIdx.x;
  if (i < NBUCK) gcur[i] = i * BCAP;
}

// ---- binned CSR pass 1 (1024 thr: 16 waves/block for LDS-atomic latency) ----
// record: (dst_local<<17) | src   (src < 2^17, dst_local < 256)
__global__ __launch_bounds__(1024) void k_bin1(const int* __restrict__ ei,
    int* __restrict__ gcur, u32* __restrict__ binned) {
  __shared__ int cnt[NBUCK];
  __shared__ int base[NBUCK];
  int t = threadIdx.x;
  int e0 = blockIdx.x * CHUNK;
  for (int j = t; j < NBUCK; j += 1024) cnt[j] = 0;
  __syncthreads();
  for (int j = 0; j < CHUNK / 1024; ++j) {
    int e = e0 + j * 1024 + t;
    if (e < N_EDGES) {
      unsigned d = (unsigned)ei[N_EDGES + e];
      if (d < N_NODES) atomicAdd(&cnt[d >> 8], 1);
    }
  }
  __syncthreads();
  for (int j = t; j < NBUCK; j += 1024)
    base[j] = cnt[j] ? atomicAdd(&gcur[j], cnt[j]) : 0;
  __syncthreads();
  for (int j = 0; j < CHUNK / 1024; ++j) {
    int e = e0 + j * 1024 + t;
    if (e < N_EDGES) {
      unsigned s = (unsigned)ei[e];
      unsigned d = (unsigned)ei[N_EDGES + e];
      if (s < N_NODES && d < N_NODES) {
        int b = d >> 8;
        int pos = atomicAdd(&base[b], 1);
        if ((unsigned)pos < NPADE)
          binned[pos] = ((d & 255u) << 17) | s;
      }
    }
  }
}

// ---- pass 2 (1024 thr): per-bucket histogram + guarded 256-scan + scatter ---
__global__ __launch_bounds__(1024) void k_bin2(const u32* __restrict__ binned,
    const int* __restrict__ gcur, int* __restrict__ rp, int* __restrict__ re,
    float* __restrict__ dinv, int* __restrict__ ed) {
  __shared__ int cnt[256];
  __shared__ int s[256];
  __shared__ int cur[256];
  int b = blockIdx.x, t = threadIdx.x;
  int start = b * BCAP, end = gcur[b];
  if (t < 256) cnt[t] = 0;
  __syncthreads();
  for (int i = start + t; i < end; i += 1024)
    atomicAdd(&cnt[binned[i] >> 17], 1);
  __syncthreads();
  int v = (t < 256) ? cnt[t] : 0;
  if (t < 256) s[t] = v;
  __syncthreads();
  for (int off = 1; off < 256; off <<= 1) {
    int add = (t >= off && t < 256) ? s[t - off] : 0;
    __syncthreads();
    if (t < 256) s[t] += add;
    __syncthreads();
  }
  if (t < 256) {
    int excl = s[t] - v;
    int n = b * 256 + t;
    if (n < N_NODES) {
      rp[n] = start + excl;
      re[n] = start + excl + v;
      dinv[n] = rsqrtf((float)v + 1.0f);   // +1 self-loop
    }
    cur[t] = start + excl;
  }
  __syncthreads();
  for (int i = start + t; i < end; i += 1024) {
    u32 rec = binned[i];
    int pos = atomicAdd(&cur[rec >> 17], 1);
    if ((unsigned)pos < NPADE) ed[pos] = (int)(rec & 0x1FFFFu);
  }
}

// ---- weight transposes ------------------------------------------------------
__global__ void k_w1t(const float* __restrict__ W1, u16* __restrict__ w1t) {
  int n = blockIdx.x, k = threadIdx.x;         // 256 x 256
  w1t[n * 256 + k] = f2bf(W1[k * 256 + n]);
}
__global__ void k_w2t(const float* __restrict__ W2, u16* __restrict__ w2t) {
  int n = blockIdx.x, k = threadIdx.x;         // 48 x 256 (pad cols 40..47 = 0)
  w2t[n * 256 + k] = (n < NC) ? f2bf(W2[k * NC + n]) : (u16)0;
}

// ---- GEMM1 (MFMA bf16): y'[100000,256]fp8 = dinv .* (x @ W1), 128x128 tile --
__global__ __launch_bounds__(256) void k_gemm1(const float* __restrict__ x,
    const u16* __restrict__ w1t, const float* __restrict__ dinv,
    unsigned char* __restrict__ y) {
  __shared__ char smem[20480];
  short* sA = (short*)smem;                    // [128][40] bf16 (pad 8)
  short* sB = (short*)(smem + 10240);          // [128][40]
  float* sdinv = (float*)(smem + 18432);       // 128 floats (epilogue only)
  int tid = threadIdx.x;
  int wave = tid >> 6, lane = tid & 63;
  int lq = lane >> 4, lr = lane & 15;
  int wm = (wave >> 1) * 64, wn = (wave & 1) * 64;
  int row0 = blockIdx.y * 128;
  int col0 = blockIdx.x * 128;
  int sr = tid >> 1;                           // staging row 0..127
  int sh = (tid & 1) * 16;                     // k-half in elements
  int arow = row0 + sr;
  bool aval = arow < N_NODES;
  const float* axf = x + (size_t)arow * 256 + sh;
  const u16* bx = w1t + (size_t)(col0 + sr) * 256 + sh;
  f32x4 acc[4][4] = {};
  for (int k0 = 0; k0 < 256; k0 += 32) {
    float4 f0 = {}, f1 = {}, f2 = {}, f3 = {};
    if (aval) {
      f0 = *(const float4*)(axf + k0);
      f1 = *(const float4*)(axf + k0 + 4);
      f2 = *(const float4*)(axf + k0 + 8);
      f3 = *(const float4*)(axf + k0 + 12);
    }
    uint4 vb0 = *(const uint4*)(bx + k0);
    uint4 vb1 = *(const uint4*)(bx + k0 + 8);
    uint4 pa0, pa1;
    pa0.x = (u32)f2bf(f0.x) | ((u32)f2bf(f0.y) << 16);
    pa0.y = (u32)f2bf(f0.z) | ((u32)f2bf(f0.w) << 16);
    pa0.z = (u32)f2bf(f1.x) | ((u32)f2bf(f1.y) << 16);
    pa0.w = (u32)f2bf(f1.z) | ((u32)f2bf(f1.w) << 16);
    pa1.x = (u32)f2bf(f2.x) | ((u32)f2bf(f2.y) << 16);
    pa1.y = (u32)f2bf(f2.z) | ((u32)f2bf(f2.w) << 16);
    pa1.z = (u32)f2bf(f3.x) | ((u32)f2bf(f3.y) << 16);
    pa1.w = (u32)f2bf(f3.z) | ((u32)f2bf(f3.w) << 16);
    __syncthreads();
    *(uint4*)&sA[sr * 40 + sh] = pa0;
    *(uint4*)&sA[sr * 40 + sh + 8] = pa1;
    *(uint4*)&sB[sr * 40 + sh] = vb0;
    *(uint4*)&sB[sr * 40 + sh + 8] = vb1;
    __syncthreads();
    bf16x8 af[4], bfr[4];
#pragma unroll
    for (int mt = 0; mt < 4; ++mt)
      af[mt] = *(const bf16x8*)&sA[(wm + mt * 16 + lr) * 40 + lq * 8];
#pragma unroll
    for (int nt = 0; nt < 4; ++nt)
      bfr[nt] = *(const bf16x8*)&sB[(wn + nt * 16 + lr) * 40 + lq * 8];
#pragma unroll
    for (int mt = 0; mt < 4; ++mt)
#pragma unroll
      for (int nt = 0; nt < 4; ++nt)
        acc[mt][nt] = __builtin_amdgcn_mfma_f32_16x16x32_bf16(
            af[mt], bfr[nt], acc[mt][nt], 0, 0, 0);
  }
  __syncthreads();
  if (tid < 128) {
    int rr = row0 + tid;
    sdinv[tid] = (rr < N_NODES) ? dinv[rr] : 0.f;
  }
  __syncthreads();
#pragma unroll
  for (int mt = 0; mt < 4; ++mt)
#pragma unroll
    for (int nt = 0; nt < 4; ++nt) {
      int c = wn + nt * 16 + lr;
#pragma unroll
      for (int i = 0; i < 4; ++i) {
        int r = wm + mt * 16 + lq * 4 + i;
        float sv = sdinv[r] * acc[mt][nt][i];
        int pk = __builtin_amdgcn_cvt_pk_fp8_f32(sv, sv, 0, false);
        smem[r * 144 + c] = (char)(pk & 0xFF);
      }
    }
  __syncthreads();
  if (aval) {
    unsigned char* dst = y + (size_t)arow * 256 + col0 + (tid & 1) * 64;
    const char* srcp = smem + sr * 144 + (tid & 1) * 64;
#pragma unroll
    for (int j = 0; j < 4; ++j)
      ((uint4*)dst)[j] = *(const uint4*)(srcp + j * 16);
  }
}

// ---- SpMM1: h1 = relu(dinv*(y'[row]+sum y'[src])+b1), half-split ------------
#define ACC8(U) do { \
    acc[0] += __builtin_amdgcn_cvt_pk_f32_fp8((U).x, false); \
    acc[1] += __builtin_amdgcn_cvt_pk_f32_fp8((U).x, true);  \
    acc[2] += __builtin_amdgcn_cvt_pk_f32_fp8((U).y, false); \
    acc[3] += __builtin_amdgcn_cvt_pk_f32_fp8((U).y, true);  \
    acc[4] += __builtin_amdgcn_cvt_pk_f32_fp8((U).z, false); \
    acc[5] += __builtin_amdgcn_cvt_pk_f32_fp8((U).z, true);  \
    acc[6] += __builtin_amdgcn_cvt_pk_f32_fp8((U).w, false); \
    acc[7] += __builtin_amdgcn_cvt_pk_f32_fp8((U).w, true);  \
  } while (0)

__global__ __launch_bounds__(256) void k_spmm1(const uint4* __restrict__ y16,
    const int* __restrict__ ed, const int* __restrict__ rp,
    const int* __restrict__ re, const float* __restrict__ dinv,
    const float* __restrict__ b1, u16* __restrict__ h1, int row0) {
  int lane = threadIdx.x & 63;
  int row = row0 + (blockIdx.x << 2) + (threadIdx.x >> 6);
  int g = lane >> 4, p = lane & 15;
  float di = dinv[row];
  uint4 sv = y16[(size_t)row * 16 + p];
  f32x2 acc[8];
  f32x2 z2 = {0.f, 0.f};
  if (g == 0) {
    acc[0] = __builtin_amdgcn_cvt_pk_f32_fp8(sv.x, false);
    acc[1] = __builtin_amdgcn_cvt_pk_f32_fp8(sv.x, true);
    acc[2] = __builtin_amdgcn_cvt_pk_f32_fp8(sv.y, false);
    acc[3] = __builtin_amdgcn_cvt_pk_f32_fp8(sv.y, true);
    acc[4] = __builtin_amdgcn_cvt_pk_f32_fp8(sv.z, false);
    acc[5] = __builtin_amdgcn_cvt_pk_f32_fp8(sv.z, true);
    acc[6] = __builtin_amdgcn_cvt_pk_f32_fp8(sv.w, false);
    acc[7] = __builtin_amdgcn_cvt_pk_f32_fp8(sv.w, true);
  } else {
#pragma unroll
    for (int i = 0; i < 8; ++i) acc[i] = z2;
  }
  int e = rp[row], e1 = re[row];
  if (e + 16 <= e1) {
    int s0 = ed[e + g], s1 = ed[e + 4 + g];
    int s2 = ed[e + 8 + g], s3 = ed[e + 12 + g];
    while (true) {
      uint4 u0 = y16[(size_t)s0 * 16 + p];
      uint4 u1 = y16[(size_t)s1 * 16 + p];
      uint4 u2 = y16[(size_t)s2 * 16 + p];
      uint4 u3 = y16[(size_t)s3 * 16 + p];
      e += 16;
      bool more = (e + 16 <= e1);
      if (more) {
        s0 = ed[e + g]; s1 = ed[e + 4 + g];
        s2 = ed[e + 8 + g]; s3 = ed[e + 12 + g];
      }
      ACC8(u0);
      ACC8(u1);
      ACC8(u2);
      ACC8(u3);
      if (!more) break;
    }
  }
  for (; e + 4 <= e1; e += 4) {
    int s0 = ed[e + g];
    uint4 u0 = y16[(size_t)s0 * 16 + p];
    ACC8(u0);
  }
  int rem = e1 - e;
  if (rem > 0) {
    int s0 = ed[e + (g < rem ? g : 0)];
    uint4 u0 = y16[(size_t)s0 * 16 + p];
    if (g < rem) ACC8(u0);
  }
#pragma unroll
  for (int i = 0; i < 8; ++i) {
    acc[i].x += __shfl_xor(acc[i].x, 16);
    acc[i].y += __shfl_xor(acc[i].y, 16);
    acc[i].x += __shfl_xor(acc[i].x, 32);
    acc[i].y += __shfl_xor(acc[i].y, 32);
  }
  if (g == 0) {
    const float4* bb4 = (const float4*)(b1 + p * 16);
    u16 o[16];
#pragma unroll
    for (int i = 0; i < 4; ++i) {
      float4 bb = bb4[i];
      float a0 = fmaxf(di * acc[2 * i].x + bb.x, 0.f);
      float a1 = fmaxf(di * acc[2 * i].y + bb.y, 0.f);
      float a2 = fmaxf(di * acc[2 * i + 1].x + bb.z, 0.f);
      float a3 = fmaxf(di * acc[2 * i + 1].y + bb.w, 0.f);
      o[4 * i + 0] = f2bf(a0);
      o[4 * i + 1] = f2bf(a1);
      o[4 * i + 2] = f2bf(a2);
      o[4 * i + 3] = f2bf(a3);
    }
    u16* dst = h1 + (size_t)row * HID + p * 16;
    *(uint4*)dst = *(const uint4*)&o[0];
    *(uint4*)(dst + 8) = *(const uint4*)&o[8];
  }
}

// ---- GEMM2 (MFMA bf16): z'[100000,64]bf16 = dinv .* (h1 @ W2), padded cols --
__global__ __launch_bounds__(256) void k_gemm2(const u16* __restrict__ h1,
    const u16* __restrict__ w2t, const float* __restrict__ dinv,
    u16* __restrict__ zbp) {
  __shared__ char smem[16384];
  short* sA = (short*)smem;                    // [128][40] bf16
  short* sB = (short*)(smem + 10240);          // [48][40]
  float* sdinv = (float*)(smem + 14336);       // 128 floats
  u16* sC = (u16*)smem;                        // [128][56] epilogue overlay
  int tid = threadIdx.x;
  int wave = tid >> 6, lane = tid & 63;
  int lq = lane >> 4, lr = lane & 15;
  int wm = wave * 32;
  int row0 = blockIdx.x * 128;
  int sr = tid >> 1;
  int sh = (tid & 1) * 16;
  int arow = row0 + sr;
  bool aval = arow < N_NODES;
  const u16* ax = h1 + (size_t)arow * 256 + sh;
  int br = tid >> 1;                           // B staging row (t<96)
  const u16* bx = w2t + (size_t)br * 256 + sh;
  if (tid < 128) {
    int rr = row0 + tid;
    sdinv[tid] = (rr < N_NODES) ? dinv[rr] : 0.f;
  }
  f32x4 acc[2][3] = {};
  for (int k0 = 0; k0 < 256; k0 += 32) {
    uint4 a0 = {}, a1 = {};
    if (aval) {
      a0 = *(const uint4*)(ax + k0);
      a1 = *(const uint4*)(ax + k0 + 8);
    }
    uint4 b0 = {}, b1v = {};
    if (tid < 96) {
      b0 = *(const uint4*)(bx + k0);
      b1v = *(const uint4*)(bx + k0 + 8);
    }
    __syncthreads();
    *(uint4*)&sA[sr * 40 + sh] = a0;
    *(uint4*)&sA[sr * 40 + sh + 8] = a1;
    if (tid < 96) {
      *(uint4*)&sB[br * 40 + sh] = b0;
      *(uint4*)&sB[br * 40 + sh + 8] = b1v;
    }
    __syncthreads();
    bf16x8 af[2], bfr[3];
#pragma unroll
    for (int mt = 0; mt < 2; ++mt)
      af[mt] = *(const bf16x8*)&sA[(wm + mt * 16 + lr) * 40 + lq * 8];
#pragma unroll
    for (int nt = 0; nt < 3; ++nt)
      bfr[nt] = *(const bf16x8*)&sB[(nt * 16 + lr) * 40 + lq * 8];
#pragma unroll
    for (int mt = 0; mt < 2; ++mt)
#pragma unroll
      for (int nt = 0; nt < 3; ++nt)
        acc[mt][nt] = __builtin_amdgcn_mfma_f32_16x16x32_bf16(
            af[mt], bfr[nt], acc[mt][nt], 0, 0, 0);
  }
  __syncthreads();
#pragma unroll
  for (int mt = 0; mt < 2; ++mt)
#pragma unroll
    for (int nt = 0; nt < 3; ++nt) {
      int c = nt * 16 + lr;
#pragma unroll
      for (int i = 0; i < 4; ++i) {
        int r = wm + mt * 16 + lq * 4 + i;
        sC[r * 56 + c] = f2bf(sdinv[r] * acc[mt][nt][i]);
      }
    }
  __syncthreads();
  if (tid < 128) {
    int orow = row0 + tid;
    if (orow < N_NODES) {
      u16* dst = zbp + (size_t)orow * 64;      // 128 B per row, padded
#pragma unroll
      for (int j = 0; j < 6; ++j)
        ((uint4*)dst)[j] = *(const uint4*)&sC[tid * 56 + j * 8];
      uint4 z = {};
      ((uint4*)dst)[6] = z;
      ((uint4*)dst)[7] = z;
    }
  }
}

// ---- SpMM2 + bias + log_softmax fused, half-split ---------------------------
#define ZACC(U) do { \
    acc[0] += __uint_as_float((U).x << 16); \
    acc[1] += __uint_as_float((U).x & 0xFFFF0000u); \
    acc[2] += __uint_as_float((U).y << 16); \
    acc[3] += __uint_as_float((U).y & 0xFFFF0000u); \
    acc[4] += __uint_as_float((U).z << 16); \
    acc[5] += __uint_as_float((U).z & 0xFFFF0000u); \
    acc[6] += __uint_as_float((U).w << 16); \
    acc[7] += __uint_as_float((U).w & 0xFFFF0000u); \
  } while (0)

__global__ __launch_bounds__(256) void k_spmm2(const uint4* __restrict__ zb4,
    const int* __restrict__ ed, const int* __restrict__ rp,
    const int* __restrict__ re, const float* __restrict__ dinv,
    const float* __restrict__ b2, float* __restrict__ out, int row0) {
  int lane = threadIdx.x & 63;
  int row = row0 + (blockIdx.x << 2) + (threadIdx.x >> 6);
  int g = lane >> 3, p = lane & 7;
  float di = dinv[row];
  float acc[8];
  uint4 sv = zb4[(size_t)row * 8 + p];
  if (g == 0) {
    acc[0] = __uint_as_float(sv.x << 16);
    acc[1] = __uint_as_float(sv.x & 0xFFFF0000u);
    acc[2] = __uint_as_float(sv.y << 16);
    acc[3] = __uint_as_float(sv.y & 0xFFFF0000u);
    acc[4] = __uint_as_float(sv.z << 16);
    acc[5] = __uint_as_float(sv.z & 0xFFFF0000u);
    acc[6] = __uint_as_float(sv.w << 16);
    acc[7] = __uint_as_float(sv.w & 0xFFFF0000u);
  } else {
#pragma unroll
    for (int i = 0; i < 8; ++i) acc[i] = 0.f;
  }
  int e = rp[row], e1 = re[row];
  if (e + 32 <= e1) {
    int s0 = ed[e + g], s1 = ed[e + 8 + g];
    int s2 = ed[e + 16 + g], s3 = ed[e + 24 + g];
    while (true) {
      uint4 u0 = zb4[(size_t)s0 * 8 + p];
      uint4 u1 = zb4[(size_t)s1 * 8 + p];
      uint4 u2 = zb4[(size_t)s2 * 8 + p];
      uint4 u3 = zb4[(size_t)s3 * 8 + p];
      e += 32;
      bool more = (e + 32 <= e1);
      if (more) {
        s0 = ed[e + g]; s1 = ed[e + 8 + g];
        s2 = ed[e + 16 + g]; s3 = ed[e + 24 + g];
      }
      ZACC(u0);
      ZACC(u1);
      ZACC(u2);
      ZACC(u3);
      if (!more) break;
    }
  }
  for (; e + 8 <= e1; e += 8) {
    int s0 = ed[e + g];
    uint4 u0 = zb4[(size_t)s0 * 8 + p];
    ZACC(u0);
  }
  int rem = e1 - e;
  if (g < rem) {
    int s0 = ed[e + g];
    uint4 u0 = zb4[(size_t)s0 * 8 + p];
    ZACC(u0);
  }
#pragma unroll
  for (int i = 0; i < 8; ++i) {
    acc[i] += __shfl_xor(acc[i], 8);
    acc[i] += __shfl_xor(acc[i], 16);
    acc[i] += __shfl_xor(acc[i], 32);
  }
  bool valid = p < 5;                          // cols p*8..p*8+7 < 40
  float val[8];
  if (valid) {
    float4 bb0 = *(const float4*)(b2 + p * 8);
    float4 bb1 = *(const float4*)(b2 + p * 8 + 4);
    val[0] = di * acc[0] + bb0.x;
    val[1] = di * acc[1] + bb0.y;
    val[2] = di * acc[2] + bb0.z;
    val[3] = di * acc[3] + bb0.w;
    val[4] = di * acc[4] + bb1.x;
    val[5] = di * acc[5] + bb1.y;
    val[6] = di * acc[6] + bb1.z;
    val[7] = di * acc[7] + bb1.w;
  } else {
#pragma unroll
    for (int i = 0; i < 8; ++i) val[i] = 0.f;
  }
  float mv = -3.0e38f;
  if (valid) {
#pragma unroll
    for (int i = 0; i < 8; ++i) mv = fmaxf(mv, val[i]);
  }
  mv = fmaxf(mv, __shfl_xor(mv, 1));
  mv = fmaxf(mv, __shfl_xor(mv, 2));
  mv = fmaxf(mv, __shfl_xor(mv, 4));
  float sum = 0.f;
  if (valid) {
#pragma unroll
    for (int i = 0; i < 8; ++i) sum += expf(val[i] - mv);
  }
  sum += __shfl_xor(sum, 1);
  sum += __shfl_xor(sum, 2);
  sum += __shfl_xor(sum, 4);
  float ls = logf(sum);
  if (g == 0 && valid) {
    float4 o0, o1;
    o0.x = val[0] - mv - ls; o0.y = val[1] - mv - ls;
    o0.z = val[2] - mv - ls; o0.w = val[3] - mv - ls;
    o1.x = val[4] - mv - ls; o1.y = val[5] - mv - ls;
    o1.z = val[6] - mv - ls; o1.w = val[7] - mv - ls;
    float* dst = out + (size_t)row * NC + p * 8;
    *(float4*)dst = o0;
    *(float4*)(dst + 4) = o1;
  }
}

extern "C" void kernel_launch(void* const* d_in, const int* in_sizes, int n_in,
                              void* d_out, int out_size, void* d_ws, size_t ws_size,
                              hipStream_t stream) {
  const float* x  = (const float*)d_in[0];
  const int*   ei = (const int*)d_in[1];
  const float* W1 = (const float*)d_in[2];
  const float* b1 = (const float*)d_in[3];
  const float* W2 = (const float*)d_in[4];
  const float* b2 = (const float*)d_in[5];
  float* out = (float*)d_out;

  char* ws = (char*)d_ws;
  size_t off = 0;
  auto alloc = [&](size_t bytes) {
    char* p = ws + off;
    off = (off + bytes + 255) & ~(size_t)255;
    return p;
  };
  int*   gcur   = (int*)  alloc((size_t)NBUCK * 4);
  int*   rp     = (int*)  alloc((size_t)N_NODES * 4);
  int*   re     = (int*)  alloc((size_t)N_NODES * 4);
  float* dinv   = (float*)alloc((size_t)N_NODES * 4);
  u32*   binned = (u32*)  alloc((size_t)NPADE * 4);             // 25.6 MB
  int*   ed     = (int*)  alloc((size_t)NPADE * 4);             // 25.6 MB
  unsigned char* y = (unsigned char*)alloc((size_t)N_NODES * 256); // 25.6 MB fp8
  u16*   w1t    = (u16*)  alloc((size_t)256 * 256 * 2);
  u16*   w2t    = (u16*)  alloc((size_t)48 * 256 * 2);
  u16*   h1     = (u16*)  alloc((size_t)N_NODES * HID * 2);     // 51.2 MB
  u16*   zbp    = (u16*)  alloc((size_t)N_NODES * 64 * 2);      // 12.8 MB padded

  k_zero<<<2, 256, 0, stream>>>(gcur);
  k_bin1<<<BIN1_BLOCKS, 1024, 0, stream>>>(ei, gcur, binned);
  k_bin2<<<NBUCK, 1024, 0, stream>>>(binned, gcur, rp, re, dinv, ed);
  k_w1t<<<256, 256, 0, stream>>>(W1, w1t);
  k_w2t<<<48, 256, 0, stream>>>(W2, w2t);
  k_gemm1<<<dim3(2, (N_NODES + 127) / 128), 256, 0, stream>>>(x, w1t, dinv, y);
  k_spmm1<<<N_NODES / 8, 256, 0, stream>>>((const uint4*)y, ed, rp, re, dinv, b1, h1, 0);
  k_spmm1<<<N_NODES / 8, 256, 0, stream>>>((const uint4*)y, ed, rp, re, dinv, b1, h1, N_NODES / 2);
  k_gemm2<<<(N_NODES + 127) / 128, 256, 0, stream>>>(h1, w2t, dinv, zbp);
  k_spmm2<<<N_NODES / 8, 256, 0, stream>>>((const uint4*)zbp, ed, rp, re, dinv, b2, out, 0);
  k_spmm2<<<N_NODES / 8, 256, 0, stream>>>((const uint4*)zbp, ed, rp, re, dinv, b2, out, N_NODES / 2);
}